// Round 4
// baseline (244.940 us; speedup 1.0000x reference)
//
#include <hip/hip_runtime.h>
#include <cmath>

#define NB 256
#define NS 8192
#define NF 2048
#define NK 20

typedef _Float16 half8 __attribute__((ext_vector_type(8)));
typedef _Float16 half4 __attribute__((ext_vector_type(4)));
typedef float f32x4 __attribute__((ext_vector_type(4)));

__device__ __forceinline__ float waveSum(float v) {
#pragma unroll
  for (int off = 32; off > 0; off >>= 1) v += __shfl_xor(v, off, 64);
  return v;
}
__device__ __forceinline__ float waveMax(float v) {
#pragma unroll
  for (int off = 32; off > 0; off >>= 1) v = fmaxf(v, __shfl_xor(v, off, 64));
  return v;
}

// ============ K1: prep ============
// blocks [0,512): row stats -> mll, alpha_h   (block 0 also zeroes loss accums)
// blocks [512,1024): Pt transpose (16 cols/block), RAW exp fp16
// blocks [1024,1280): normalize x -> xh fp16
// blocks [1280,1536): block 1280+b zeroes Wp rows {b, 256+b} then builds the
//   neighbor-weight entries for batch item b (row ownership disjoint -> no race)
__global__ __launch_bounds__(256, 1) void prep(
    const float* __restrict__ in0, const float* __restrict__ logits0,
    const float* __restrict__ logits1, const int* __restrict__ neighbors,
    const float* __restrict__ ndist, _Float16* __restrict__ Pt,
    _Float16* __restrict__ xh, _Float16* __restrict__ alpha_h,
    float* __restrict__ mll, _Float16* __restrict__ Wp,
    float* __restrict__ loss) {
  __shared__ alignas(16) union {
    struct {
      float redA[4];
      float redB[4];
    } s;
    _Float16 Lt[16 * 520];  // 16.25 KB
  } sm;
  int tid = threadIdx.x, blk = blockIdx.x;
  int wave = tid >> 6, lane = tid & 63;

  if (blk < 512) {
    // ---- row stats ----
    if (blk == 0 && tid < 3) loss[tid] = 0.0f;
    int r = blk;
    const float* src = (r < NB) ? logits0 : logits1;
    const float4* row = (const float4*)(src + (size_t)(r & (NB - 1)) * NS);
    float4 v[8];
    float mx = -1e30f;
#pragma unroll
    for (int i = 0; i < 8; ++i) {
      v[i] = row[tid + i * 256];
      mx = fmaxf(mx, fmaxf(fmaxf(v[i].x, v[i].y), fmaxf(v[i].z, v[i].w)));
    }
    float wv = waveMax(mx);
    if (lane == 0) sm.s.redA[wave] = wv;
    __syncthreads();
    float m = fmaxf(fmaxf(sm.s.redA[0], sm.s.redA[1]), fmaxf(sm.s.redA[2], sm.s.redA[3]));
    float se = 0.0f;
#pragma unroll
    for (int i = 0; i < 8; ++i)
      se += expf(v[i].x - m) + expf(v[i].y - m) + expf(v[i].z - m) + expf(v[i].w - m);
    float sw = waveSum(se);
    if (lane == 0) sm.s.redB[wave] = sw;
    __syncthreads();
    float l = (sm.s.redB[0] + sm.s.redB[1]) + (sm.s.redB[2] + sm.s.redB[3]);
    if (tid == 0) {
      mll[r] = m + logf(l);
      alpha_h[r] = (_Float16)(256.0f * expf(-m) / l);
    }
  } else if (blk < 1024) {
    // ---- Pt transpose (raw exp), 16 columns per block ----
    int s0 = (blk - 512) * 16;
#pragma unroll
    for (int g = 0; g < 8; ++g) {
      int pos = g * 256 + tid;
      int row = pos >> 2, c4 = pos & 3;
      const float* src = ((row < NB) ? logits0 + (size_t)row * NS
                                     : logits1 + (size_t)(row - NB) * NS) + s0 + c4 * 4;
      float4 v = *(const float4*)src;
      sm.Lt[(c4 * 4 + 0) * 520 + row] = (_Float16)expf(v.x);
      sm.Lt[(c4 * 4 + 1) * 520 + row] = (_Float16)expf(v.y);
      sm.Lt[(c4 * 4 + 2) * 520 + row] = (_Float16)expf(v.z);
      sm.Lt[(c4 * 4 + 3) * 520 + row] = (_Float16)expf(v.w);
    }
    __syncthreads();
    int srow = tid >> 4, seg = tid & 15;
    _Float16* dst = Pt + (size_t)(s0 + srow) * 512 + seg * 32;
    const _Float16* lsrc = &sm.Lt[srow * 520 + seg * 32];
#pragma unroll
    for (int q = 0; q < 4; ++q)
      *(half8*)(dst + q * 8) = *(const half8*)(lsrc + q * 8);
  } else if (blk < 1280) {
    // ---- normalize x -> xh ----
    int b = blk - 1024;
    const float4* row = (const float4*)(in0 + (size_t)b * NF);
    float4 v0 = row[tid], v1 = row[tid + 256];
    float ss = v0.x * v0.x + v0.y * v0.y + v0.z * v0.z + v0.w * v0.w +
               v1.x * v1.x + v1.y * v1.y + v1.z * v1.z + v1.w * v1.w;
    float w = waveSum(ss);
    if (lane == 0) sm.s.redA[wave] = w;
    __syncthreads();
    float tot = (sm.s.redA[0] + sm.s.redA[1]) + (sm.s.redA[2] + sm.s.redA[3]);
    float inv = 1.0f / fmaxf(sqrtf(tot), 1e-12f);
    half4 h0, h1;
    h0[0] = (_Float16)(v0.x * inv); h0[1] = (_Float16)(v0.y * inv);
    h0[2] = (_Float16)(v0.z * inv); h0[3] = (_Float16)(v0.w * inv);
    h1[0] = (_Float16)(v1.x * inv); h1[1] = (_Float16)(v1.y * inv);
    h1[2] = (_Float16)(v1.z * inv); h1[3] = (_Float16)(v1.w * inv);
    ((half4*)(xh + (size_t)b * NF))[tid] = h0;
    ((half4*)(xh + (size_t)b * NF))[tid + 256] = h1;
  } else {
    // ---- weight rows for batch item b: zero rows {b, 256+b}, then fill ----
    int b = blk - 1280;
    _Float16* rkl = Wp + (size_t)b * 512;
    _Float16* rce = Wp + (size_t)(256 + b) * 512;
    if (tid < 64) ((float4*)rkl)[tid] = make_float4(0, 0, 0, 0);
    else if (tid < 128) ((float4*)rce)[tid - 64] = make_float4(0, 0, 0, 0);
    __syncthreads();
    if (tid == 0) {
      float d[NK], e[NK];
      int n[NK];
      float s = 0.0f;
      int cnt = 0;
#pragma unroll
      for (int k = 0; k < NK; ++k) {
        d[k] = ndist[b * NK + k];
        n[k] = neighbors[b * NK + k];
        e[k] = expf(d[k] * (1.0f / 0.6f));
        s += e[k];
        cnt += (d[k] <= 2.0f) ? 1 : 0;
      }
      float invs = 1.0f / (2.0f * s);
      float invc = 1.0f / fmaxf((float)cnt, 1.0f);
#pragma unroll
      for (int k = 0; k < NK; ++k) {
        bool first = true;
#pragma unroll
        for (int k2 = 0; k2 < NK; ++k2)
          if (k2 < k && n[k2] == n[k]) first = false;
        if (first) {
          float wsum = 0.0f, ksum = 0.0f;
#pragma unroll
          for (int k2 = 0; k2 < NK; ++k2)
            if (k2 >= k && n[k2] == n[k]) {
              wsum += e[k2] * invs;
              ksum += (d[k2] <= 2.0f) ? invc : 0.0f;
            }
          rkl[n[k]] = (_Float16)ksum;
          rce[n[k]] = (_Float16)wsum;
          rce[256 + n[k]] = (_Float16)wsum;
        }
      }
    }
  }
}

// ============ K2: both GEMMs, LDS-free direct-fragment + copy ============
// blocks [0,256): scores = x@F^T (128x64 tile), fragments loaded straight from
//   global (xh fp16 -> af; fp32 features -> convert -> bf). No LDS, no barriers.
//   Waves 2x2: 64 rows x 32 cols each. Fused 32-col-stripe LSE + target pick.
// blocks [256,512): T = W@P (128x128 tile), direct-fragment, alpha k-scale,
//   fused CE/KL epilogue.
// blocks [512,768): features -> outF streaming copy (32 rows/block).
__global__ __launch_bounds__(256, 3) void gemms(
    const _Float16* __restrict__ xh, const float* __restrict__ fB,
    const _Float16* __restrict__ Wp, const _Float16* __restrict__ Pt,
    const _Float16* __restrict__ alpha_h,
    const float* __restrict__ logits0, const float* __restrict__ logits1,
    const float* __restrict__ mll, const int* __restrict__ targets,
    float* __restrict__ outF, float* __restrict__ pm, float* __restrict__ pl,
    float* __restrict__ tgt, float* __restrict__ part) {
  __shared__ float red[4];
  int tid = threadIdx.x, wave = tid >> 6, lane = tid & 63;
  int quad = lane >> 4, r16 = lane & 15;
  int blk = blockIdx.x;
  if (blk < 256) {
    int bx = blk & 127, by = blk >> 7;
    int n0 = bx * 64, m0 = by * 128;
    int wmr = m0 + (wave >> 1) * 64 + r16;       // A row base (+i*16)
    int wnc = n0 + (wave & 1) * 32 + r16;        // B row base (+j*16)
    const _Float16* pa[4];
    const float* pb[2];
#pragma unroll
    for (int i = 0; i < 4; ++i) pa[i] = xh + (size_t)(wmr + i * 16) * NF + quad * 8;
#pragma unroll
    for (int j = 0; j < 2; ++j) pb[j] = fB + (size_t)(wnc + j * 16) * NF + quad * 8;
    f32x4 acc[4][2] = {};
#pragma unroll 2
    for (int kk = 0; kk < NF; kk += 32) {
      half8 af[4], bf[2];
#pragma unroll
      for (int j = 0; j < 2; ++j) {
        float4 lo = *(const float4*)(pb[j] + kk);
        float4 hi = *(const float4*)(pb[j] + kk + 4);
        half8 h;
        h[0] = (_Float16)lo.x; h[1] = (_Float16)lo.y;
        h[2] = (_Float16)lo.z; h[3] = (_Float16)lo.w;
        h[4] = (_Float16)hi.x; h[5] = (_Float16)hi.y;
        h[6] = (_Float16)hi.z; h[7] = (_Float16)hi.w;
        bf[j] = h;
      }
#pragma unroll
      for (int i = 0; i < 4; ++i) af[i] = *(const half8*)(pa[i] + kk);
#pragma unroll
      for (int i = 0; i < 4; ++i)
#pragma unroll
        for (int j = 0; j < 2; ++j)
          acc[i][j] = __builtin_amdgcn_mfma_f32_16x16x32_f16(af[i], bf[j], acc[i][j], 0, 0, 0);
    }
    int sx = bx * 2 + (wave & 1);  // 32-col stripe index in [0,256)
#pragma unroll
    for (int i = 0; i < 4; ++i)
#pragma unroll
      for (int r = 0; r < 4; ++r) {
        int R = m0 + (wave >> 1) * 64 + i * 16 + quad * 4 + r;
        float s0 = acc[i][0][r] * 20.0f, s1 = acc[i][1][r] * 20.0f;  // 1/TEMP
        float mx = fmaxf(s0, s1);
#pragma unroll
        for (int m2 = 1; m2 < 16; m2 <<= 1) mx = fmaxf(mx, __shfl_xor(mx, m2, 64));
        float e = expf(s0 - mx) + expf(s1 - mx);
#pragma unroll
        for (int m2 = 1; m2 < 16; m2 <<= 1) e += __shfl_xor(e, m2, 64);
        int tg = targets[R];
        if (wnc == tg) tgt[R] = s0;
        if (wnc + 16 == tg) tgt[R] = s1;
        if (r16 == 0) { pm[R * 256 + sx] = mx; pl[R * 256 + sx] = e; }
      }
  } else if (blk < 512) {
    int nb = blk - 256;
    int bx = nb & 63, by = nb >> 6;
    int n0 = bx * 128, m0 = by * 128;
    int wm = (wave >> 1) * 64, wn = (wave & 1) * 64;
    const _Float16* pa[4];
    const _Float16* pb[4];
#pragma unroll
    for (int i = 0; i < 4; ++i)
      pa[i] = Wp + (size_t)(m0 + wm + i * 16 + r16) * 512 + quad * 8;
#pragma unroll
    for (int j = 0; j < 4; ++j)
      pb[j] = Pt + (size_t)(n0 + wn + j * 16 + r16) * 512 + quad * 8;
    const _Float16* pal = alpha_h + quad * 8;
    f32x4 acc[4][4] = {};
#pragma unroll 2
    for (int kk = 0; kk < 512; kk += 32) {
      half8 alv = *(const half8*)(pal + kk);
      half8 af[4], bf[4];
#pragma unroll
      for (int i = 0; i < 4; ++i) af[i] = *(const half8*)(pa[i] + kk);
#pragma unroll
      for (int j = 0; j < 4; ++j) bf[j] = *(const half8*)(pb[j] + kk) * alv;
#pragma unroll
      for (int i = 0; i < 4; ++i)
#pragma unroll
        for (int j = 0; j < 4; ++j)
          acc[i][j] = __builtin_amdgcn_mfma_f32_16x16x32_f16(af[i], bf[j], acc[i][j], 0, 0, 0);
    }
    bool iskl = (by < 2);
    const float* lgbase = iskl ? logits1 : logits0;
    float local = 0.0f;
#pragma unroll
    for (int i = 0; i < 4; ++i)
#pragma unroll
      for (int r = 0; r < 4; ++r) {
        int Mg = m0 + wm + i * 16 + quad * 4 + r;
        int b = iskl ? Mg : (Mg - 256);
        float mv = mll[iskl ? 256 + b : b];
        const float* lgrow = lgbase + (size_t)b * NS + n0 + wn;
#pragma unroll
        for (int j = 0; j < 4; ++j) {
          float lg = lgrow[j * 16 + r16];
          float t = acc[i][j][r] * (1.0f / 256.0f);
          if (iskl)
            local += (t > 0.0f) ? t * (logf(fmaxf(t, 1e-12f)) - (lg - mv)) : 0.0f;
          else
            local += -0.1f * t * (lg - mv);
        }
      }
    float wsv = waveSum(local);
    if (lane == 0) red[wave] = wsv;
    __syncthreads();
    if (tid == 0) part[nb] = (red[0] + red[1]) + (red[2] + red[3]);
  } else {
    // ---- features -> outF streaming copy, 32 rows/block ----
    int r0 = (blk - 512) * 32;
    const float4* src = (const float4*)fB + (size_t)r0 * 512;
    float4* dst = (float4*)outF + (size_t)r0 * 512;
    for (int i = tid; i < 32 * 512; i += 256) dst[i] = src[i];
  }
}

// ============ K3: finalize + momentum winner rows ============
// blocks [0,256): LSE over 256 stripes of row b + CE-onehot + part[] -> atomics
// blocks [256,512): block 256+b: if b is the LAST occurrence of targets[b],
//   recompute momentum+renorm row and overwrite outF[targets[b]].
__global__ __launch_bounds__(128) void final_reduce(
    const float* __restrict__ pm, const float* __restrict__ pl,
    const float* __restrict__ tgt, const float* __restrict__ part,
    const float* __restrict__ logits0, const float* __restrict__ mll,
    const int* __restrict__ targets, const float* __restrict__ rampup,
    const float* __restrict__ in0, const float* __restrict__ features,
    float* __restrict__ outF, float* __restrict__ out) {
  __shared__ float rA[2], rB[2];
  __shared__ int flag;
  int tid = threadIdx.x, blk = blockIdx.x;
  if (blk < 256) {
    int b = blk;
    float m1 = pm[b * 256 + tid], m2v = pm[b * 256 + 128 + tid];
    float l1 = pl[b * 256 + tid], l2v = pl[b * 256 + 128 + tid];
    float wm = waveMax(fmaxf(m1, m2v));
    if ((tid & 63) == 0) rA[tid >> 6] = wm;
    __syncthreads();
    float mx = fmaxf(rA[0], rA[1]);
    float e = l1 * expf(m1 - mx) + l2v * expf(m2v - mx);
    float ws = waveSum(e);
    if ((tid & 63) == 0) rB[tid >> 6] = ws;
    __syncthreads();
    if (tid == 0) {
      float S = rB[0] + rB[1];
      float nce = -(tgt[b] - mx - logf(S));
      int tg = targets[b];
      float oh = -0.9f * (logits0[(size_t)b * NS + tg] - mll[b]);
      float pb = part[b];
      float v1 = oh;
      if (b >= 128) v1 += pb;  // CE partials live at part[128..255]
      atomicAdd(out + 0, nce * (1.0f / 256.0f));
      atomicAdd(out + 1, v1 * (1.0f / 256.0f));
      if (b < 128) atomicAdd(out + 2, rampup[0] * pb * (1.0f / 256.0f));
    }
  } else {
    int b = blk - 256;
    int tg = targets[b];
    if (tid == 0) flag = 0;
    __syncthreads();
    bool later = false;
    for (int i = b + 1 + tid; i < 256; i += 128) later = later || (targets[i] == tg);
    if (later) flag = 1;
    __syncthreads();
    if (flag) return;  // some later batch row owns this target
    const float4* xr = (const float4*)(in0 + (size_t)b * NF);
    const float4* fr = (const float4*)(features + (size_t)tg * NF);
    float4 a[4];
    float ssx = 0.0f;
#pragma unroll
    for (int s = 0; s < 4; ++s) {
      a[s] = xr[tid + s * 128];
      ssx += a[s].x * a[s].x + a[s].y * a[s].y + a[s].z * a[s].z + a[s].w * a[s].w;
    }
    float w1 = waveSum(ssx);
    if ((tid & 63) == 0) rA[tid >> 6] = w1;
    __syncthreads();
    float ix = 0.8f / fmaxf(sqrtf(rA[0] + rA[1]), 1e-12f);
    float4 v[4];
    float ss = 0.0f;
#pragma unroll
    for (int s = 0; s < 4; ++s) {
      float4 f = fr[tid + s * 128];
      v[s] = make_float4(0.2f * f.x + ix * a[s].x, 0.2f * f.y + ix * a[s].y,
                         0.2f * f.z + ix * a[s].z, 0.2f * f.w + ix * a[s].w);
      ss += v[s].x * v[s].x + v[s].y * v[s].y + v[s].z * v[s].z + v[s].w * v[s].w;
    }
    float w2 = waveSum(ss);
    if ((tid & 63) == 0) rB[tid >> 6] = w2;
    __syncthreads();
    float inv = 1.0f / fmaxf(sqrtf(rB[0] + rB[1]), 1e-12f);
    float4* o4 = (float4*)(outF + (size_t)tg * NF);
#pragma unroll
    for (int s = 0; s < 4; ++s)
      o4[tid + s * 128] = make_float4(v[s].x * inv, v[s].y * inv, v[s].z * inv, v[s].w * inv);
  }
}

extern "C" void kernel_launch(void* const* d_in, const int* in_sizes, int n_in,
                              void* d_out, int out_size, void* d_ws, size_t ws_size,
                              hipStream_t stream) {
  const float* inputs0 = (const float*)d_in[0];
  const float* logits0 = (const float*)d_in[1];
  const float* logits1 = (const float*)d_in[2];
  const int* targets = (const int*)d_in[3];
  const int* neighbors = (const int*)d_in[5];
  const float* ndist = (const float*)d_in[6];
  const float* rampup = (const float*)d_in[7];
  const float* features = (const float*)d_in[8];
  float* out = (float*)d_out;

  char* ws = (char*)d_ws;
  float* mll = (float*)(ws + 4096);             // 2 KB
  _Float16* alpha_h = (_Float16*)(ws + 8192);   // 1 KB
  float* part = (float*)(ws + 12288);           // 1 KB
  float* tgt = (float*)(ws + 16384);            // 1 KB
  float* pm = (float*)(ws + 65536);             // 256 KB (256 rows x 256 stripes)
  float* pl = (float*)(ws + 65536 + 262144);    // 256 KB
  _Float16* Wp = (_Float16*)(ws + (1 << 20));   // 512 KB
  _Float16* xh = (_Float16*)(ws + (3 << 20));   // 1 MB
  _Float16* Pt = (_Float16*)(ws + (4 << 20));   // 8 MB

  prep<<<1536, 256, 0, stream>>>(inputs0, logits0, logits1, neighbors, ndist,
                                 Pt, xh, alpha_h, mll, Wp, out);
  gemms<<<768, 256, 0, stream>>>(xh, features, Wp, Pt, alpha_h, logits0, logits1,
                                 mll, targets, out + 3, pm, pl, tgt, part);
  final_reduce<<<512, 128, 0, stream>>>(pm, pl, tgt, part, logits0, mll, targets,
                                        rampup, inputs0, features, out + 3, out);
}

// Round 5
// 215.718 us; speedup vs baseline: 1.1355x; 1.1355x over previous
//
#include <hip/hip_runtime.h>
#include <cmath>

#define NB 256
#define NS 8192
#define NF 2048
#define NK 20

typedef _Float16 half8 __attribute__((ext_vector_type(8)));
typedef _Float16 half4 __attribute__((ext_vector_type(4)));
typedef float f32x4 __attribute__((ext_vector_type(4)));

__device__ __forceinline__ void async16(const void* g, void* l) {
  __builtin_amdgcn_global_load_lds(
      (const __attribute__((address_space(1))) unsigned int*)g,
      (__attribute__((address_space(3))) unsigned int*)l, 16, 0, 0);
}

__device__ __forceinline__ float waveSum(float v) {
#pragma unroll
  for (int off = 32; off > 0; off >>= 1) v += __shfl_xor(v, off, 64);
  return v;
}
__device__ __forceinline__ float waveMax(float v) {
#pragma unroll
  for (int off = 32; off > 0; off >>= 1) v = fmaxf(v, __shfl_xor(v, off, 64));
  return v;
}

// ============ K1: prep ============
// blocks [0,512): FUSED row stats + raw-exp P write (one logits pass).
//   block r: m, l -> mll[r], alpha[r] (f32); P[r][s] = exp(l[r][s]) fp16.
// blocks [512,768): normalize x -> xh fp16.
__global__ __launch_bounds__(256) void prep(
    const float* __restrict__ in0, const float* __restrict__ logits0,
    const float* __restrict__ logits1, _Float16* __restrict__ P,
    _Float16* __restrict__ xh, float* __restrict__ alpha,
    float* __restrict__ mll, float* __restrict__ loss) {
  __shared__ float redA[4], redB[4];
  int tid = threadIdx.x, blk = blockIdx.x;
  int wave = tid >> 6, lane = tid & 63;

  if (blk < 512) {
    if (blk == 0 && tid < 3) loss[tid] = 0.0f;  // zero loss accumulators
    int r = blk;
    const float* src = (r < NB) ? logits0 : logits1;
    const float4* row = (const float4*)(src + (size_t)(r & (NB - 1)) * NS);
    float4 v[8];
    float mx = -1e30f;
#pragma unroll
    for (int i = 0; i < 8; ++i) {
      v[i] = row[tid + i * 256];
      mx = fmaxf(mx, fmaxf(fmaxf(v[i].x, v[i].y), fmaxf(v[i].z, v[i].w)));
    }
    float wv = waveMax(mx);
    if (lane == 0) redA[wave] = wv;
    __syncthreads();
    float m = fmaxf(fmaxf(redA[0], redA[1]), fmaxf(redA[2], redA[3]));
    float em = expf(m);
    float se = 0.0f;
    half4* prow = (half4*)(P + (size_t)r * NS);
#pragma unroll
    for (int i = 0; i < 8; ++i) {
      float e0 = expf(v[i].x - m), e1 = expf(v[i].y - m);
      float e2 = expf(v[i].z - m), e3 = expf(v[i].w - m);
      se += (e0 + e1) + (e2 + e3);
      half4 h;
      h[0] = (_Float16)(e0 * em); h[1] = (_Float16)(e1 * em);
      h[2] = (_Float16)(e2 * em); h[3] = (_Float16)(e3 * em);
      prow[tid + i * 256] = h;
    }
    float sw = waveSum(se);
    if (lane == 0) redB[wave] = sw;
    __syncthreads();
    float l = (redB[0] + redB[1]) + (redB[2] + redB[3]);
    if (tid == 0) {
      mll[r] = m + logf(l);
      alpha[r] = 256.0f * expf(-m) / l;
    }
  } else {
    // ---- normalize x -> xh ----
    int b = blk - 512;
    const float4* row = (const float4*)(in0 + (size_t)b * NF);
    float4 v0 = row[tid], v1 = row[tid + 256];
    float ss = v0.x * v0.x + v0.y * v0.y + v0.z * v0.z + v0.w * v0.w +
               v1.x * v1.x + v1.y * v1.y + v1.z * v1.z + v1.w * v1.w;
    float w = waveSum(ss);
    if (lane == 0) redA[wave] = w;
    __syncthreads();
    float tot = (redA[0] + redA[1]) + (redA[2] + redA[3]);
    float inv = 1.0f / fmaxf(sqrtf(tot), 1e-12f);
    half4 h0, h1;
    h0[0] = (_Float16)(v0.x * inv); h0[1] = (_Float16)(v0.y * inv);
    h0[2] = (_Float16)(v0.z * inv); h0[3] = (_Float16)(v0.w * inv);
    h1[0] = (_Float16)(v1.x * inv); h1[1] = (_Float16)(v1.y * inv);
    h1[2] = (_Float16)(v1.z * inv); h1[3] = (_Float16)(v1.w * inv);
    ((half4*)(xh + (size_t)b * NF))[tid] = h0;
    ((half4*)(xh + (size_t)b * NF))[tid + 256] = h1;
  }
}

// ============ K2: GEMM1 (staged) + sparse neighbor-gather CE/KL ============
// blocks [0,128): scores = x@F^T. Block = full M=256 x 64 features rows.
//   B (features, HBM) reg-staged -> fp16 LDS (XOR chunks) + fused outF store;
//   A (xh, L2-hot) via async16 -> LDS. Waves split M (64 rows each).
//   Fused per-row 64-col LSE stripe + target pick.
// blocks [128,1152): gather block (b, s-slice of 2048): T_CE/T_KL as sparse
//   20-neighbor weighted sums over P rows (L2), fused CE/KL epilogue over
//   logits0/1, atomicAdd into out[1], out[2].
__global__ __launch_bounds__(256) void fused2(
    const _Float16* __restrict__ xh, const float* __restrict__ fB,
    const _Float16* __restrict__ P, const float* __restrict__ alpha,
    const float* __restrict__ mll, const float* __restrict__ logits0,
    const float* __restrict__ logits1, const int* __restrict__ targets,
    const int* __restrict__ neighbors, const float* __restrict__ ndist,
    const float* __restrict__ rampup, float* __restrict__ outF,
    float* __restrict__ pm, float* __restrict__ pl, float* __restrict__ tgt,
    float* __restrict__ out) {
  __shared__ alignas(16) _Float16 As[256 * 64];  // 32 KB
  __shared__ alignas(16) _Float16 Bs[64 * 64];   // 8 KB
  __shared__ float red[8];
  int tid = threadIdx.x, wave = tid >> 6, lane = tid & 63;
  int quad = lane >> 4, r16 = lane & 15;
  int blk = blockIdx.x;

  if (blk < 128) {
    int n0 = blk * 64;
    int srow = tid >> 2, scg = tid & 3;  // B staging: row, 16-float col group
    f32x4 acc[4][4] = {};
    for (int k0 = 0; k0 < NF; k0 += 64) {
      // B fp32 loads (issued ahead of the barrier)
      float4 fv[4];
      const float* bsrc = fB + (size_t)(n0 + srow) * NF + k0 + scg * 16;
#pragma unroll
      for (int q = 0; q < 4; ++q) fv[q] = *(const float4*)(bsrc + q * 4);
      __syncthreads();  // previous tile fully consumed
      // A tile: 256 rows x 64 cols fp16 via async16, pre-swizzled source
#pragma unroll
      for (int ss = 0; ss < 8; ++ss) {
        int rl = ss * 32 + (tid >> 3);
        int sc = (tid & 7) ^ (rl & 7);
        async16(xh + (size_t)rl * NF + k0 + sc * 8, &As[rl * 64 + (tid & 7) * 8]);
      }
      // B convert -> swizzled LDS + fused outF store
#pragma unroll
      for (int h = 0; h < 2; ++h) {
        half8 hh;
        hh[0] = (_Float16)fv[2 * h].x; hh[1] = (_Float16)fv[2 * h].y;
        hh[2] = (_Float16)fv[2 * h].z; hh[3] = (_Float16)fv[2 * h].w;
        hh[4] = (_Float16)fv[2 * h + 1].x; hh[5] = (_Float16)fv[2 * h + 1].y;
        hh[6] = (_Float16)fv[2 * h + 1].z; hh[7] = (_Float16)fv[2 * h + 1].w;
        int p = (scg * 2 + h) ^ (srow & 7);
        *(half8*)&Bs[srow * 64 + p * 8] = hh;
      }
      float4* odst = (float4*)(outF + (size_t)(n0 + srow) * NF + k0 + scg * 16);
#pragma unroll
      for (int q = 0; q < 4; ++q) odst[q] = fv[q];
      __syncthreads();  // tile ready
#pragma unroll
      for (int sub = 0; sub < 2; ++sub) {
        int slot = ((sub * 4 + quad) ^ (r16 & 7)) * 8;
        half8 af[4], bf[4];
#pragma unroll
        for (int i = 0; i < 4; ++i)
          af[i] = *(const half8*)&As[(wave * 64 + i * 16 + r16) * 64 + slot];
#pragma unroll
        for (int j = 0; j < 4; ++j)
          bf[j] = *(const half8*)&Bs[(j * 16 + r16) * 64 + slot];
#pragma unroll
        for (int i = 0; i < 4; ++i)
#pragma unroll
          for (int j = 0; j < 4; ++j)
            acc[i][j] = __builtin_amdgcn_mfma_f32_16x16x32_f16(af[i], bf[j], acc[i][j], 0, 0, 0);
      }
    }
    // epilogue: per-row LSE over this block's 64 cols -> stripe blk
#pragma unroll
    for (int i = 0; i < 4; ++i)
#pragma unroll
      for (int r = 0; r < 4; ++r) {
        int R = wave * 64 + i * 16 + quad * 4 + r;
        float sv[4];
#pragma unroll
        for (int j = 0; j < 4; ++j) sv[j] = acc[i][j][r] * 20.0f;  // 1/TEMP
        float mx = fmaxf(fmaxf(sv[0], sv[1]), fmaxf(sv[2], sv[3]));
#pragma unroll
        for (int m2 = 1; m2 < 16; m2 <<= 1) mx = fmaxf(mx, __shfl_xor(mx, m2, 64));
        float e = expf(sv[0] - mx) + expf(sv[1] - mx) + expf(sv[2] - mx) + expf(sv[3] - mx);
#pragma unroll
        for (int m2 = 1; m2 < 16; m2 <<= 1) e += __shfl_xor(e, m2, 64);
        int tg = targets[R];
#pragma unroll
        for (int j = 0; j < 4; ++j)
          if (n0 + j * 16 + r16 == tg) tgt[R] = sv[j];
        if (r16 == 0) { pm[R * 128 + blk] = mx; pl[R * 128 + blk] = e; }
      }
  } else {
    // ---- sparse neighbor-gather CE/KL ----
    int gb = blk - 128;
    int b = gb >> 2, s0 = (gb & 3) * 2048;
    // pass 1: softmax-weight normalizer + consistency count (uniform scalars)
    float s = 0.0f;
    int cnt = 0;
#pragma unroll
    for (int k = 0; k < NK; ++k) {
      float d = ndist[b * NK + k];
      s += expf(d * (1.0f / 0.6f));
      cnt += (d <= 2.0f) ? 1 : 0;
    }
    float invs = 1.0f / (2.0f * s);
    float invc = 1.0f / fmaxf((float)cnt, 1.0f);
    float ce[8] = {0, 0, 0, 0, 0, 0, 0, 0};
    float kl[8] = {0, 0, 0, 0, 0, 0, 0, 0};
    int sc_ = s0 + tid * 8;
#pragma unroll 4
    for (int k = 0; k < NK; ++k) {
      float d = ndist[b * NK + k];
      int n = neighbors[b * NK + k];
      float wce = expf(d * (1.0f / 0.6f)) * invs;
      float wkl = (d <= 2.0f) ? invc : 0.0f;
      float a0 = alpha[n], a1 = alpha[256 + n];
      float c0 = wce * a0, c1 = wce * a1, ck = wkl * a0;
      half8 p0 = *(const half8*)(P + (size_t)n * NS + sc_);
      half8 p1 = *(const half8*)(P + (size_t)(256 + n) * NS + sc_);
#pragma unroll
      for (int e2 = 0; e2 < 8; ++e2) {
        float q0 = (float)p0[e2], q1 = (float)p1[e2];
        ce[e2] += c0 * q0 + c1 * q1;
        kl[e2] += ck * q0;
      }
    }
    float mv0 = mll[b], mv1 = mll[256 + b];
    const float* g0 = logits0 + (size_t)b * NS + sc_;
    const float* g1 = logits1 + (size_t)b * NS + sc_;
    float4 l0a = *(const float4*)g0, l0b = *(const float4*)(g0 + 4);
    float4 l1a = *(const float4*)g1, l1b = *(const float4*)(g1 + 4);
    float lg0[8] = {l0a.x, l0a.y, l0a.z, l0a.w, l0b.x, l0b.y, l0b.z, l0b.w};
    float lg1[8] = {l1a.x, l1a.y, l1a.z, l1a.w, l1b.x, l1b.y, l1b.z, l1b.w};
    float lce = 0.0f, lkl = 0.0f;
#pragma unroll
    for (int e2 = 0; e2 < 8; ++e2) {
      float t = ce[e2] * (1.0f / 256.0f);
      lce += t * (lg0[e2] - mv0);
      float tk = kl[e2] * (1.0f / 256.0f);
      lkl += (tk > 0.0f) ? tk * (logf(fmaxf(tk, 1e-12f)) - (lg1[e2] - mv1)) : 0.0f;
    }
    float wc = waveSum(lce), wk = waveSum(lkl);
    if (lane == 0) { red[wave] = wc; red[4 + wave] = wk; }
    __syncthreads();
    if (tid == 0) {
      float ce_t = (red[0] + red[1]) + (red[2] + red[3]);
      float kl_t = (red[4] + red[5]) + (red[6] + red[7]);
      atomicAdd(out + 1, -0.1f * ce_t * (1.0f / 256.0f));
      atomicAdd(out + 2, rampup[0] * kl_t * (1.0f / 256.0f));
    }
  }
}

// ============ K3: finalize + momentum winner rows ============
// blocks [0,256): LSE over 128 stripes of row b + CE-onehot -> atomics
// blocks [256,512): block 256+b: if b is the LAST occurrence of targets[b],
//   recompute momentum+renorm row and overwrite outF[targets[b]].
__global__ __launch_bounds__(128) void final_reduce(
    const float* __restrict__ pm, const float* __restrict__ pl,
    const float* __restrict__ tgt, const float* __restrict__ logits0,
    const float* __restrict__ mll, const int* __restrict__ targets,
    const float* __restrict__ in0, const float* __restrict__ features,
    float* __restrict__ outF, float* __restrict__ out) {
  __shared__ float rA[2], rB[2];
  __shared__ int flag;
  int tid = threadIdx.x, blk = blockIdx.x;
  if (blk < 256) {
    int b = blk;
    float m = pm[b * 128 + tid];
    float l = pl[b * 128 + tid];
    float wm = waveMax(m);
    if ((tid & 63) == 0) rA[tid >> 6] = wm;
    __syncthreads();
    float mx = fmaxf(rA[0], rA[1]);
    float e = l * expf(m - mx);
    float ws = waveSum(e);
    if ((tid & 63) == 0) rB[tid >> 6] = ws;
    __syncthreads();
    if (tid == 0) {
      float S = rB[0] + rB[1];
      float nce = -(tgt[b] - mx - logf(S));
      int tg = targets[b];
      float oh = -0.9f * (logits0[(size_t)b * NS + tg] - mll[b]);
      atomicAdd(out + 0, nce * (1.0f / 256.0f));
      atomicAdd(out + 1, oh * (1.0f / 256.0f));
    }
  } else {
    int b = blk - 256;
    int tg = targets[b];
    if (tid == 0) flag = 0;
    __syncthreads();
    bool later = false;
    for (int i = b + 1 + tid; i < 256; i += 128) later = later || (targets[i] == tg);
    if (later) flag = 1;
    __syncthreads();
    if (flag) return;  // some later batch row owns this target
    const float4* xr = (const float4*)(in0 + (size_t)b * NF);
    const float4* fr = (const float4*)(features + (size_t)tg * NF);
    float4 a[4];
    float ssx = 0.0f;
#pragma unroll
    for (int s = 0; s < 4; ++s) {
      a[s] = xr[tid + s * 128];
      ssx += a[s].x * a[s].x + a[s].y * a[s].y + a[s].z * a[s].z + a[s].w * a[s].w;
    }
    float w1 = waveSum(ssx);
    if ((tid & 63) == 0) rA[tid >> 6] = w1;
    __syncthreads();
    float ix = 0.8f / fmaxf(sqrtf(rA[0] + rA[1]), 1e-12f);
    float4 v[4];
    float ss = 0.0f;
#pragma unroll
    for (int s = 0; s < 4; ++s) {
      float4 f = fr[tid + s * 128];
      v[s] = make_float4(0.2f * f.x + ix * a[s].x, 0.2f * f.y + ix * a[s].y,
                         0.2f * f.z + ix * a[s].z, 0.2f * f.w + ix * a[s].w);
      ss += v[s].x * v[s].x + v[s].y * v[s].y + v[s].z * v[s].z + v[s].w * v[s].w;
    }
    float w2 = waveSum(ss);
    if ((tid & 63) == 0) rB[tid >> 6] = w2;
    __syncthreads();
    float inv = 1.0f / fmaxf(sqrtf(rB[0] + rB[1]), 1e-12f);
    float4* o4 = (float4*)(outF + (size_t)tg * NF);
#pragma unroll
    for (int s = 0; s < 4; ++s)
      o4[tid + s * 128] = make_float4(v[s].x * inv, v[s].y * inv, v[s].z * inv, v[s].w * inv);
  }
}

extern "C" void kernel_launch(void* const* d_in, const int* in_sizes, int n_in,
                              void* d_out, int out_size, void* d_ws, size_t ws_size,
                              hipStream_t stream) {
  const float* inputs0 = (const float*)d_in[0];
  const float* logits0 = (const float*)d_in[1];
  const float* logits1 = (const float*)d_in[2];
  const int* targets = (const int*)d_in[3];
  const int* neighbors = (const int*)d_in[5];
  const float* ndist = (const float*)d_in[6];
  const float* rampup = (const float*)d_in[7];
  const float* features = (const float*)d_in[8];
  float* out = (float*)d_out;

  char* ws = (char*)d_ws;
  float* mll = (float*)(ws + 4096);            // 2 KB
  float* alpha = (float*)(ws + 8192);          // 2 KB (f32 now)
  float* tgt = (float*)(ws + 16384);           // 1 KB
  float* pm = (float*)(ws + 65536);            // 128 KB (256 rows x 128 stripes)
  float* pl = (float*)(ws + 196608);           // 128 KB
  _Float16* xh = (_Float16*)(ws + (3 << 20));  // 1 MB
  _Float16* P = (_Float16*)(ws + (4 << 20));   // 8 MB (row-major raw exp)

  prep<<<768, 256, 0, stream>>>(inputs0, logits0, logits1, P, xh, alpha, mll, out);
  fused2<<<1152, 256, 0, stream>>>(xh, features, P, alpha, mll, logits0, logits1,
                                   targets, neighbors, ndist, rampup, out + 3,
                                   pm, pl, tgt, out);
  final_reduce<<<512, 128, 0, stream>>>(pm, pl, tgt, logits0, mll, targets,
                                        inputs0, features, out + 3, out);
}

// Round 6
// 204.742 us; speedup vs baseline: 1.1963x; 1.0536x over previous
//
#include <hip/hip_runtime.h>
#include <cmath>

#define NB 256
#define NS 8192
#define NF 2048
#define NK 20

typedef _Float16 half8 __attribute__((ext_vector_type(8)));
typedef _Float16 half4 __attribute__((ext_vector_type(4)));
typedef float f32x4 __attribute__((ext_vector_type(4)));

__device__ __forceinline__ void async16(const void* g, void* l) {
  __builtin_amdgcn_global_load_lds(
      (const __attribute__((address_space(1))) unsigned int*)g,
      (__attribute__((address_space(3))) unsigned int*)l, 16, 0, 0);
}

__device__ __forceinline__ float waveSum(float v) {
#pragma unroll
  for (int off = 32; off > 0; off >>= 1) v += __shfl_xor(v, off, 64);
  return v;
}
__device__ __forceinline__ float waveMax(float v) {
#pragma unroll
  for (int off = 32; off > 0; off >>= 1) v = fmaxf(v, __shfl_xor(v, off, 64));
  return v;
}

// ============ K1: prep ============
// blocks [0,512): FUSED row stats + raw-exp P write (one logits pass).
//   block r: m, l -> mll[r], alpha[r] (f32); P[r][s] = exp(l[r][s]) fp16.
// blocks [512,768): normalize x -> xh fp16.
__global__ __launch_bounds__(256) void prep(
    const float* __restrict__ in0, const float* __restrict__ logits0,
    const float* __restrict__ logits1, _Float16* __restrict__ P,
    _Float16* __restrict__ xh, float* __restrict__ alpha,
    float* __restrict__ mll, float* __restrict__ loss) {
  __shared__ float redA[4], redB[4];
  int tid = threadIdx.x, blk = blockIdx.x;
  int wave = tid >> 6, lane = tid & 63;

  if (blk < 512) {
    if (blk == 0 && tid < 3) loss[tid] = 0.0f;  // zero loss accumulators
    int r = blk;
    const float* src = (r < NB) ? logits0 : logits1;
    const float4* row = (const float4*)(src + (size_t)(r & (NB - 1)) * NS);
    float4 v[8];
    float mx = -1e30f;
#pragma unroll
    for (int i = 0; i < 8; ++i) {
      v[i] = row[tid + i * 256];
      mx = fmaxf(mx, fmaxf(fmaxf(v[i].x, v[i].y), fmaxf(v[i].z, v[i].w)));
    }
    float wv = waveMax(mx);
    if (lane == 0) redA[wave] = wv;
    __syncthreads();
    float m = fmaxf(fmaxf(redA[0], redA[1]), fmaxf(redA[2], redA[3]));
    float em = expf(m);
    float se = 0.0f;
    half4* prow = (half4*)(P + (size_t)r * NS);
#pragma unroll
    for (int i = 0; i < 8; ++i) {
      float e0 = expf(v[i].x - m), e1 = expf(v[i].y - m);
      float e2 = expf(v[i].z - m), e3 = expf(v[i].w - m);
      se += (e0 + e1) + (e2 + e3);
      half4 h;
      h[0] = (_Float16)(e0 * em); h[1] = (_Float16)(e1 * em);
      h[2] = (_Float16)(e2 * em); h[3] = (_Float16)(e3 * em);
      prow[tid + i * 256] = h;
    }
    float sw = waveSum(se);
    if (lane == 0) redB[wave] = sw;
    __syncthreads();
    float l = (redB[0] + redB[1]) + (redB[2] + redB[3]);
    if (tid == 0) {
      mll[r] = m + logf(l);
      alpha[r] = 256.0f * expf(-m) / l;
    }
  } else {
    // ---- normalize x -> xh ----
    int b = blk - 512;
    const float4* row = (const float4*)(in0 + (size_t)b * NF);
    float4 v0 = row[tid], v1 = row[tid + 256];
    float ss = v0.x * v0.x + v0.y * v0.y + v0.z * v0.z + v0.w * v0.w +
               v1.x * v1.x + v1.y * v1.y + v1.z * v1.z + v1.w * v1.w;
    float w = waveSum(ss);
    if (lane == 0) redA[wave] = w;
    __syncthreads();
    float tot = (redA[0] + redA[1]) + (redA[2] + redA[3]);
    float inv = 1.0f / fmaxf(sqrtf(tot), 1e-12f);
    half4 h0, h1;
    h0[0] = (_Float16)(v0.x * inv); h0[1] = (_Float16)(v0.y * inv);
    h0[2] = (_Float16)(v0.z * inv); h0[3] = (_Float16)(v0.w * inv);
    h1[0] = (_Float16)(v1.x * inv); h1[1] = (_Float16)(v1.y * inv);
    h1[2] = (_Float16)(v1.z * inv); h1[3] = (_Float16)(v1.w * inv);
    ((half4*)(xh + (size_t)b * NF))[tid] = h0;
    ((half4*)(xh + (size_t)b * NF))[tid + 256] = h1;
  }
}

// ============ K2: GEMM1 (128x64 tiles, 256 blocks) + sparse gather CE/KL ============
// blocks [0,256): scores = x@F^T. Tile M=128 (by=blk>>7) x N=64 (bx=blk&127),
//   BK=64, 2-barrier staged loop: B (features fp32, HBM) reg->fp16 LDS with
//   XOR-chunk swizzle; A (xh, L2-hot) async16 with pre-swizzled source; outF
//   store K-half-split across by and issued AFTER the barrier (overlaps MFMA).
//   Fused per-row 64-col LSE stripe + target pick.
// blocks [256,1280): gather block (b, s-slice): sparse 20-neighbor weighted
//   sums over P rows (L3-hot), fused CE/KL epilogue, atomicAdd out[1],out[2].
//   GEMM blocks first so they start at t=0; gather blocks backfill all CUs.
__global__ __launch_bounds__(256) void fused2(
    const _Float16* __restrict__ xh, const float* __restrict__ fB,
    const _Float16* __restrict__ P, const float* __restrict__ alpha,
    const float* __restrict__ mll, const float* __restrict__ logits0,
    const float* __restrict__ logits1, const int* __restrict__ targets,
    const int* __restrict__ neighbors, const float* __restrict__ ndist,
    const float* __restrict__ rampup, float* __restrict__ outF,
    float* __restrict__ pm, float* __restrict__ pl, float* __restrict__ tgt,
    float* __restrict__ out) {
  __shared__ alignas(16) _Float16 As[128 * 64];  // 16 KB
  __shared__ alignas(16) _Float16 Bs[64 * 64];   // 8 KB
  __shared__ float red[8];
  int tid = threadIdx.x, wave = tid >> 6, lane = tid & 63;
  int quad = lane >> 4, r16 = lane & 15;
  int blk = blockIdx.x;

  if (blk < 256) {
    int bx = blk & 127, by = blk >> 7;
    int n0 = bx * 64, m0 = by * 128;
    int brow = tid >> 2, bcg = tid & 3;  // B staging: row (64), 16-float group
    f32x4 acc[2][4] = {};
    for (int k0 = 0; k0 < NF; k0 += 64) {
      // B fp32 loads issued ahead of the barrier (latency overlaps prev MFMA)
      float4 fv[4];
      const float* bsrc = fB + (size_t)(n0 + brow) * NF + k0 + bcg * 16;
#pragma unroll
      for (int q = 0; q < 4; ++q) fv[q] = *(const float4*)(bsrc + q * 4);
      __syncthreads();  // previous tile fully consumed
      // A tile: 128 rows x 64 cols via async16, pre-swizzled source column
#pragma unroll
      for (int ss = 0; ss < 4; ++ss) {
        int rl = ss * 32 + (tid >> 3);
        int sc = (tid & 7) ^ (rl & 7);
        async16(xh + (size_t)(m0 + rl) * NF + k0 + sc * 8,
                &As[rl * 64 + (tid & 7) * 8]);
      }
      // B convert -> XOR-swizzled LDS (chunk c8 ^ row&7)
#pragma unroll
      for (int h = 0; h < 2; ++h) {
        half8 hh;
        hh[0] = (_Float16)fv[2 * h].x; hh[1] = (_Float16)fv[2 * h].y;
        hh[2] = (_Float16)fv[2 * h].z; hh[3] = (_Float16)fv[2 * h].w;
        hh[4] = (_Float16)fv[2 * h + 1].x; hh[5] = (_Float16)fv[2 * h + 1].y;
        hh[6] = (_Float16)fv[2 * h + 1].z; hh[7] = (_Float16)fv[2 * h + 1].w;
        int c8 = bcg * 2 + h;
        *(half8*)&Bs[brow * 64 + ((c8 ^ (brow & 7)) << 3)] = hh;
      }
      __syncthreads();  // tile ready (drains async16 + ds_write)
      // outF store AFTER the barrier: overlaps the MFMA phase, drains at the
      // next iteration's first barrier. K-half split balances the two by-blocks.
      if (by == (k0 >= NF / 2)) {
        float4* odst = (float4*)(outF + (size_t)(n0 + brow) * NF + k0 + bcg * 16);
#pragma unroll
        for (int q = 0; q < 4; ++q) odst[q] = fv[q];
      }
#pragma unroll
      for (int sub = 0; sub < 2; ++sub) {
        int slot = ((sub * 4 + quad) ^ (r16 & 7)) * 8;
        half8 af[2], bf[4];
#pragma unroll
        for (int i = 0; i < 2; ++i)
          af[i] = *(const half8*)&As[(wave * 32 + i * 16 + r16) * 64 + slot];
#pragma unroll
        for (int j = 0; j < 4; ++j)
          bf[j] = *(const half8*)&Bs[(j * 16 + r16) * 64 + slot];
#pragma unroll
        for (int i = 0; i < 2; ++i)
#pragma unroll
          for (int j = 0; j < 4; ++j)
            acc[i][j] = __builtin_amdgcn_mfma_f32_16x16x32_f16(af[i], bf[j], acc[i][j], 0, 0, 0);
      }
    }
    // epilogue: per-row LSE over this block's 64 cols -> stripe bx
#pragma unroll
    for (int i = 0; i < 2; ++i)
#pragma unroll
      for (int r = 0; r < 4; ++r) {
        int R = m0 + wave * 32 + i * 16 + quad * 4 + r;
        float sv[4];
#pragma unroll
        for (int j = 0; j < 4; ++j) sv[j] = acc[i][j][r] * 20.0f;  // 1/TEMP
        float mx = fmaxf(fmaxf(sv[0], sv[1]), fmaxf(sv[2], sv[3]));
#pragma unroll
        for (int m2 = 1; m2 < 16; m2 <<= 1) mx = fmaxf(mx, __shfl_xor(mx, m2, 64));
        float e = expf(sv[0] - mx) + expf(sv[1] - mx) + expf(sv[2] - mx) + expf(sv[3] - mx);
#pragma unroll
        for (int m2 = 1; m2 < 16; m2 <<= 1) e += __shfl_xor(e, m2, 64);
        int tg = targets[R];
#pragma unroll
        for (int j = 0; j < 4; ++j)
          if (n0 + j * 16 + r16 == tg) tgt[R] = sv[j];
        if (r16 == 0) { pm[R * 128 + bx] = mx; pl[R * 128 + bx] = e; }
      }
  } else {
    // ---- sparse neighbor-gather CE/KL ----
    int gb = blk - 256;
    int b = gb >> 2, s0 = (gb & 3) * 2048;
    float s = 0.0f;
    int cnt = 0;
#pragma unroll
    for (int k = 0; k < NK; ++k) {
      float d = ndist[b * NK + k];
      s += expf(d * (1.0f / 0.6f));
      cnt += (d <= 2.0f) ? 1 : 0;
    }
    float invs = 1.0f / (2.0f * s);
    float invc = 1.0f / fmaxf((float)cnt, 1.0f);
    float ce[8] = {0, 0, 0, 0, 0, 0, 0, 0};
    float kl[8] = {0, 0, 0, 0, 0, 0, 0, 0};
    int sc_ = s0 + tid * 8;
#pragma unroll 4
    for (int k = 0; k < NK; ++k) {
      float d = ndist[b * NK + k];
      int n = neighbors[b * NK + k];
      float wce = expf(d * (1.0f / 0.6f)) * invs;
      float wkl = (d <= 2.0f) ? invc : 0.0f;
      float a0 = alpha[n], a1 = alpha[256 + n];
      float c0 = wce * a0, c1 = wce * a1, ck = wkl * a0;
      half8 p0 = *(const half8*)(P + (size_t)n * NS + sc_);
      half8 p1 = *(const half8*)(P + (size_t)(256 + n) * NS + sc_);
#pragma unroll
      for (int e2 = 0; e2 < 8; ++e2) {
        float q0 = (float)p0[e2], q1 = (float)p1[e2];
        ce[e2] += c0 * q0 + c1 * q1;
        kl[e2] += ck * q0;
      }
    }
    float mv0 = mll[b], mv1 = mll[256 + b];
    const float* g0 = logits0 + (size_t)b * NS + sc_;
    const float* g1 = logits1 + (size_t)b * NS + sc_;
    float4 l0a = *(const float4*)g0, l0b = *(const float4*)(g0 + 4);
    float4 l1a = *(const float4*)g1, l1b = *(const float4*)(g1 + 4);
    float lg0[8] = {l0a.x, l0a.y, l0a.z, l0a.w, l0b.x, l0b.y, l0b.z, l0b.w};
    float lg1[8] = {l1a.x, l1a.y, l1a.z, l1a.w, l1b.x, l1b.y, l1b.z, l1b.w};
    float lce = 0.0f, lkl = 0.0f;
#pragma unroll
    for (int e2 = 0; e2 < 8; ++e2) {
      float t = ce[e2] * (1.0f / 256.0f);
      lce += t * (lg0[e2] - mv0);
      float tk = kl[e2] * (1.0f / 256.0f);
      lkl += (tk > 0.0f) ? tk * (logf(fmaxf(tk, 1e-12f)) - (lg1[e2] - mv1)) : 0.0f;
    }
    float wc = waveSum(lce), wk = waveSum(lkl);
    if (lane == 0) { red[wave] = wc; red[4 + wave] = wk; }
    __syncthreads();
    if (tid == 0) {
      float ce_t = (red[0] + red[1]) + (red[2] + red[3]);
      float kl_t = (red[4] + red[5]) + (red[6] + red[7]);
      atomicAdd(out + 1, -0.1f * ce_t * (1.0f / 256.0f));
      atomicAdd(out + 2, rampup[0] * kl_t * (1.0f / 256.0f));
    }
  }
}

// ============ K3: finalize + momentum winner rows ============
// blocks [0,256): LSE over 128 stripes of row b + CE-onehot -> atomics
// blocks [256,512): block 256+b: if b is the LAST occurrence of targets[b],
//   recompute momentum+renorm row and overwrite outF[targets[b]].
__global__ __launch_bounds__(128) void final_reduce(
    const float* __restrict__ pm, const float* __restrict__ pl,
    const float* __restrict__ tgt, const float* __restrict__ logits0,
    const float* __restrict__ mll, const int* __restrict__ targets,
    const float* __restrict__ in0, const float* __restrict__ features,
    float* __restrict__ outF, float* __restrict__ out) {
  __shared__ float rA[2], rB[2];
  __shared__ int flag;
  int tid = threadIdx.x, blk = blockIdx.x;
  if (blk < 256) {
    int b = blk;
    float m = pm[b * 128 + tid];
    float l = pl[b * 128 + tid];
    float wm = waveMax(m);
    if ((tid & 63) == 0) rA[tid >> 6] = wm;
    __syncthreads();
    float mx = fmaxf(rA[0], rA[1]);
    float e = l * expf(m - mx);
    float ws = waveSum(e);
    if ((tid & 63) == 0) rB[tid >> 6] = ws;
    __syncthreads();
    if (tid == 0) {
      float S = rB[0] + rB[1];
      float nce = -(tgt[b] - mx - logf(S));
      int tg = targets[b];
      float oh = -0.9f * (logits0[(size_t)b * NS + tg] - mll[b]);
      atomicAdd(out + 0, nce * (1.0f / 256.0f));
      atomicAdd(out + 1, oh * (1.0f / 256.0f));
    }
  } else {
    int b = blk - 256;
    int tg = targets[b];
    if (tid == 0) flag = 0;
    __syncthreads();
    bool later = false;
    for (int i = b + 1 + tid; i < 256; i += 128) later = later || (targets[i] == tg);
    if (later) flag = 1;
    __syncthreads();
    if (flag) return;  // some later batch row owns this target
    const float4* xr = (const float4*)(in0 + (size_t)b * NF);
    const float4* fr = (const float4*)(features + (size_t)tg * NF);
    float4 a[4];
    float ssx = 0.0f;
#pragma unroll
    for (int s = 0; s < 4; ++s) {
      a[s] = xr[tid + s * 128];
      ssx += a[s].x * a[s].x + a[s].y * a[s].y + a[s].z * a[s].z + a[s].w * a[s].w;
    }
    float w1 = waveSum(ssx);
    if ((tid & 63) == 0) rA[tid >> 6] = w1;
    __syncthreads();
    float ix = 0.8f / fmaxf(sqrtf(rA[0] + rA[1]), 1e-12f);
    float4 v[4];
    float ss = 0.0f;
#pragma unroll
    for (int s = 0; s < 4; ++s) {
      float4 f = fr[tid + s * 128];
      v[s] = make_float4(0.2f * f.x + ix * a[s].x, 0.2f * f.y + ix * a[s].y,
                         0.2f * f.z + ix * a[s].z, 0.2f * f.w + ix * a[s].w);
      ss += v[s].x * v[s].x + v[s].y * v[s].y + v[s].z * v[s].z + v[s].w * v[s].w;
    }
    float w2 = waveSum(ss);
    if ((tid & 63) == 0) rB[tid >> 6] = w2;
    __syncthreads();
    float inv = 1.0f / fmaxf(sqrtf(rB[0] + rB[1]), 1e-12f);
    float4* o4 = (float4*)(outF + (size_t)tg * NF);
#pragma unroll
    for (int s = 0; s < 4; ++s)
      o4[tid + s * 128] = make_float4(v[s].x * inv, v[s].y * inv, v[s].z * inv, v[s].w * inv);
  }
}

extern "C" void kernel_launch(void* const* d_in, const int* in_sizes, int n_in,
                              void* d_out, int out_size, void* d_ws, size_t ws_size,
                              hipStream_t stream) {
  const float* inputs0 = (const float*)d_in[0];
  const float* logits0 = (const float*)d_in[1];
  const float* logits1 = (const float*)d_in[2];
  const int* targets = (const int*)d_in[3];
  const int* neighbors = (const int*)d_in[5];
  const float* ndist = (const float*)d_in[6];
  const float* rampup = (const float*)d_in[7];
  const float* features = (const float*)d_in[8];
  float* out = (float*)d_out;

  char* ws = (char*)d_ws;
  float* mll = (float*)(ws + 4096);            // 2 KB
  float* alpha = (float*)(ws + 8192);          // 2 KB (f32)
  float* tgt = (float*)(ws + 16384);           // 1 KB
  float* pm = (float*)(ws + 65536);            // 128 KB (256 rows x 128 stripes)
  float* pl = (float*)(ws + 196608);           // 128 KB
  _Float16* xh = (_Float16*)(ws + (3 << 20));  // 1 MB
  _Float16* P = (_Float16*)(ws + (4 << 20));   // 8 MB (row-major raw exp)

  prep<<<768, 256, 0, stream>>>(inputs0, logits0, logits1, P, xh, alpha, mll, out);
  fused2<<<1280, 256, 0, stream>>>(xh, features, P, alpha, mll, logits0, logits1,
                                   targets, neighbors, ndist, rampup, out + 3,
                                   pm, pl, tgt, out);
  final_reduce<<<512, 128, 0, stream>>>(pm, pl, tgt, logits0, mll, targets,
                                        inputs0, features, out + 3, out);
}